// Round 3
// baseline (1839.819 us; speedup 1.0000x reference)
//
#include <hip/hip_runtime.h>

// LSTM, B=512 x T=1024, H=100, input_size=1.
// R7: R4-R6 counters (VGPR=56/60, FETCH~=inputs, WRITE~=output only) falsify
// the scratch-spill theory: weights live in the unified-file AGPR space and
// there is NO reload traffic. The real limiter is LDS RETURN BANDWIDTH:
// 800 threads x 26 ds_read_b128/step = 325 instr x ~1KB/instr into RF
// (~2600 cyc/step) -- broadcast does not dedupe the per-lane register fill.
// Fix: broadcast h through SGPRs instead of LDS. v_fmac_f32 takes one SGPR
// operand (free 64-lane broadcast). Decomposition: job = (row-pair, k-chunk):
//   wave w in [0,16): chunk = w>>2 (k in [25*chunk, 25*chunk+25))
//   lane: pair p = (w&3)*64+lane in [0,256), rows 2p,2p+1 (padded 400->512)
//   weights: 2x25 = 50 VGPRs/lane. Per wave/step: 1 ds_read_b32 (h chunk,
//   both batches via lane<32 / lane>=32), 50 v_readlane -> SGPR, 100 fmac.
// Partials (4 chunks) written comp-major to LDS (conflict-free both sides),
// reduced by a 200-thread cell phase (one thread = one (unit, batch): reads
// 16 partials, activations, c/h update). Phase C (out-proj) = wave 15,
// overlapped with next step's dot phase. 2 barriers/step.
// LDS instr/step: ~90 (vs 325) -> VALU-bound ~1250 cyc/step predicted.

#define HID   100
#define TLEN  1024
#define BLOCK 1024
#define KCH   25     // k-chunk size
#define NCH   4      // number of k-chunks (4*25 = 100)
#define NPAIR 256    // row-pairs incl. padding (512 rows >= 400)

__global__ __launch_bounds__(BLOCK, 4)
__attribute__((amdgpu_waves_per_eu(4, 4)))
void lstm_rl(
    const float* __restrict__ input,   // [B, T]
    const float* __restrict__ W_ih,    // [4H]
    const float* __restrict__ W_hh,    // [4H, H]
    const float* __restrict__ b_ih,    // [4H]
    const float* __restrict__ b_hh,    // [4H]
    const float* __restrict__ W_out,   // [H]
    const float* __restrict__ b_out,   // [1]
    float* __restrict__ out)           // [B, T]
{
    const int b0   = blockIdx.x * 2;
    const int tid  = threadIdx.x;
    const int lane = tid & 63;
    const int wave = tid >> 6;

    __shared__ float h0_s[128];              // h batch0 (100 used, rest 0)
    __shared__ float h1_s[128];              // h batch1
    __shared__ float part_s[4 * NCH * NPAIR];// comp-major partials, 16 KB
    __shared__ float in0_s[TLEN];
    __shared__ float in1_s[TLEN];

    // Stage both input rows (8 KB), coalesced.
    for (int i = tid; i < TLEN; i += BLOCK) {
        in0_s[i] = input[(b0 + 0) * TLEN + i];
        in1_s[i] = input[(b0 + 1) * TLEN + i];
    }

    // ---- Phase-A role: wave -> k-chunk, lane -> row-pair
    const int chunk = wave >> 2;                      // 0..3
    const int pair  = ((wave & 3) << 6) | lane;       // 0..255
    const int kb    = chunk * KCH;
    const int r0 = 2 * pair, r1 = 2 * pair + 1;
    const int wr0 = (r0 < 4 * HID) ? r0 : 4 * HID - 1;  // clamp padded rows
    const int wr1 = (r1 < 4 * HID) ? r1 : 4 * HID - 1;

    float w0[KCH], w1[KCH];                  // 50 weight VGPRs
    #pragma unroll
    for (int j = 0; j < KCH; ++j) {
        w0[j] = W_hh[wr0 * HID + kb + j];
        w1[j] = W_hh[wr1 * HID + kb + j];
    }

    // h-chunk read pointer: lanes 0..24 -> h0 chunk, lanes 32..56 -> h1 chunk
    const int hl = lane & 31;
    const float* hptr = ((lane < 32) ? h0_s : h1_s) + kb + (hl < KCH ? hl : KCH - 1);

    // ---- RB role (reduce + cell): tid<200 -> (unit u, batch rb_b)
    const int u    = (tid < 200) ? (tid % 100) : 0;
    const int rb_b = (tid < 200) ? (tid / 100) : 0;
    const float wi0 = W_ih[u],           wi1 = W_ih[100 + u];
    const float wi2 = W_ih[200 + u],     wi3 = W_ih[300 + u];
    const float bi0 = b_ih[u]       + b_hh[u];
    const float bi1 = b_ih[100 + u] + b_hh[100 + u];
    const float bi2 = b_ih[200 + u] + b_hh[200 + u];
    const float bi3 = b_ih[300 + u] + b_hh[300 + u];
    float c = 0.f;                            // cell state

    // ---- Phase-C role: wave 15 (output projection)
    const float wo0 = W_out[lane];                          // lane<64<100
    const float wo1 = (lane < HID - 64) ? W_out[64 + lane] : 0.f;
    const float bo  = b_out[0];

    if (tid < 128) { h0_s[tid] = 0.f; h1_s[tid] = 0.f; }
    __syncthreads();

    #pragma unroll 1
    for (int t = 0; t < TLEN; ++t) {
        // ---- Phase A: all 1024 lanes. SGPR-broadcast dot products.
        {
            float vh = *hptr;                 // 1 ds_read_b32 per wave
            float a00 = 0.f, a01 = 0.f, a10 = 0.f, a11 = 0.f;
            #pragma unroll
            for (int j = 0; j < KCH; ++j) {
                float s0 = __int_as_float(
                    __builtin_amdgcn_readlane(__float_as_int(vh), j));
                float s1 = __int_as_float(
                    __builtin_amdgcn_readlane(__float_as_int(vh), 32 + j));
                a00 = fmaf(s0, w0[j], a00);   // v_fmac v, s, v (SGPR bcast)
                a01 = fmaf(s0, w1[j], a01);
                a10 = fmaf(s1, w0[j], a10);
                a11 = fmaf(s1, w1[j], a11);
            }
            // comp-major partials: comp = (r&1) + 2*batch
            const int pi = (chunk << 8) | pair;
            part_s[0 * 1024 + pi] = a00;      // (r even, b0)
            part_s[1 * 1024 + pi] = a01;      // (r odd , b0)
            part_s[2 * 1024 + pi] = a10;      // (r even, b1)
            part_s[3 * 1024 + pi] = a11;      // (r odd , b1)
        }
        __syncthreads();

        // ---- RB: reduce partials + activations + cell update (200 threads)
        if (tid < 200) {
            const int comp = (u & 1) + 2 * rb_b;
            const int prb  = comp * 1024 + (u >> 1);  // + 50*g4 + 256*cc
            float s0 = 0.f, s1 = 0.f, s2 = 0.f, s3 = 0.f;
            #pragma unroll
            for (int cc = 0; cc < NCH; ++cc) {
                const float* pp = part_s + prb + (cc << 8);
                s0 += pp[0];
                s1 += pp[50];
                s2 += pp[100];
                s3 += pp[150];
            }
            const float x = rb_b ? in1_s[t] : in0_s[t];
            float ig = fmaf(x, wi0, bi0) + s0;
            float fg = fmaf(x, wi1, bi1) + s1;
            float gg = fmaf(x, wi2, bi2) + s2;
            float og = fmaf(x, wi3, bi3) + s3;
            float is = __builtin_amdgcn_rcpf(1.f + __expf(-ig));
            float fs = __builtin_amdgcn_rcpf(1.f + __expf(-fg));
            float os = __builtin_amdgcn_rcpf(1.f + __expf(-og));
            float gt = 1.f - 2.f * __builtin_amdgcn_rcpf(__expf(2.f * gg) + 1.f);
            c = fmaf(fs, c, is * gt);
            float th = 1.f - 2.f * __builtin_amdgcn_rcpf(__expf(2.f * c) + 1.f);
            (rb_b ? h1_s : h0_s)[u] = os * th;
        }
        __syncthreads();

        // ---- Phase C: out[b, t] = dot(h_new, W_out) + b_out (wave 15).
        // Overlaps next step's Phase A (A never writes h; next h write is
        // behind the next RB barrier, which wave 15 also reaches).
        if (wave == 15) {
            float p = h0_s[lane] * wo0;
            float q = h1_s[lane] * wo0;
            if (lane < HID - 64) {
                p = fmaf(h0_s[64 + lane], wo1, p);
                q = fmaf(h1_s[64 + lane], wo1, q);
            }
            #pragma unroll
            for (int off = 32; off > 0; off >>= 1) {
                p += __shfl_down(p, off);
                q += __shfl_down(q, off);
            }
            if (lane == 0) {
                out[(b0 + 0) * TLEN + t] = p + bo;
                out[(b0 + 1) * TLEN + t] = q + bo;
            }
        }
    }
}

extern "C" void kernel_launch(void* const* d_in, const int* in_sizes, int n_in,
                              void* d_out, int out_size, void* d_ws, size_t ws_size,
                              hipStream_t stream) {
    const float* input = (const float*)d_in[0];
    const float* W_ih  = (const float*)d_in[1];
    const float* W_hh  = (const float*)d_in[2];
    const float* b_ih  = (const float*)d_in[3];
    const float* b_hh  = (const float*)d_in[4];
    const float* W_out = (const float*)d_in[5];
    const float* b_out = (const float*)d_in[6];
    float* out = (float*)d_out;

    const int B = in_sizes[0] / TLEN;  // 512
    lstm_rl<<<B / 2, BLOCK, 0, stream>>>(input, W_ih, W_hh, b_ih, b_hh,
                                         W_out, b_out, out);
}

// Round 5
// 1284.075 us; speedup vs baseline: 1.4328x; 1.4328x over previous
//
#include <hip/hip_runtime.h>

// LSTM, B=512 x T=1024, H=100, input_size=1.
// R9 = R8 resubmitted verbatim (R8's bench died to an infra "container
// failed twice" error -- no kernel verdict). Audit: barriers uniform, no
// OOB, 47.6 KB LDS, no divergent-barrier deadlock path.
//
// R8 theory: unified model of R4-R7: the kernel is bound by LDS RETURN
// BANDWIDTH (~128 B/cyc/CU). R4: 800 thr x 104 h-floats/step = 83K
// lane-floats = 2600 cyc/step = measured. Traffic = 80,000/R lane-floats
// where R = rows/thread. R7's readlane fix attacked the right resource with
// the wrong tool (serial SGPR chains + 29.9M conflicts).
// This kernel: R=4, K=10. Thread (g,c) = rows 4g..4g+3, k in [10c,10c+10).
//   - 40 weight VGPRs -> fits the observed 64-arch-VGPR ceiling, no
//     v_accvgpr_read per use (R4-R6's hidden VALU tax).
//   - h reads: 20 ds_read_b32/thread, 10 distinct addrs/wave (banks 10c+j
//     mod 32 all distinct), 6-7-lane broadcast: conflict-free, 625 cyc/step.
//   - partials part_s[2][400][11] (stride 11 -> <=2-way on write & read).
// Phases: A (1000 thr: dots) | R (800 thr: reduce 10 partials + x-proj +
// activation; waves 13/14 concurrently do the t-1 output projection) |
// B (200 thr: cell update). 3 barriers/step.
// Predicted ~1500 cyc/step -> ~650 us (from 1275).

#define HID   100
#define TLEN  1024
#define BLOCK 1024
#define NROW  400            // 4*HID
#define PSTR  11             // partial stride: 10 chunks + 1 pad

__global__ __launch_bounds__(BLOCK, 4)
void lstm_kblock(
    const float* __restrict__ input,   // [B, T]
    const float* __restrict__ W_ih,    // [4H]
    const float* __restrict__ W_hh,    // [4H, H]
    const float* __restrict__ b_ih,    // [4H]
    const float* __restrict__ b_hh,    // [4H]
    const float* __restrict__ W_out,   // [H]
    const float* __restrict__ b_out,   // [1]
    float* __restrict__ out)           // [B, T]
{
    const int b0   = blockIdx.x * 2;
    const int tid  = threadIdx.x;
    const int lane = tid & 63;
    const int wave = tid >> 6;

    __shared__ float h0_s[128];                // h batch0 (100 used, pad 0)
    __shared__ float h1_s[128];
    __shared__ float part_s[2 * NROW * PSTR];  // 8800 floats = 35.2 KB
    __shared__ float g_s[2 * NROW];            // activated gates
    __shared__ float in0_s[TLEN];
    __shared__ float in1_s[TLEN];

    // Stage input rows (coalesced, one-time).
    for (int i = tid; i < TLEN; i += BLOCK) {
        in0_s[i] = input[(b0 + 0) * TLEN + i];
        in1_s[i] = input[(b0 + 1) * TLEN + i];
    }

    // ---- A role: tid<1000. g = tid/10 (rows 4g..4g+3), c = tid%10.
    const bool isA = (tid < 1000);
    const int  g   = isA ? (tid / 10) : 0;
    const int  c   = isA ? (tid % 10) : 0;
    const int  kb  = 10 * c;
    float w[4][10];                            // 40 weight VGPRs
    #pragma unroll
    for (int ro = 0; ro < 4; ++ro)
        #pragma unroll
        for (int j = 0; j < 10; ++j)
            w[ro][j] = W_hh[(4 * g + ro) * HID + kb + j];

    // ---- R role: tid<800. rr = row, rb = batch.
    const int  rr = (tid < 400) ? tid : (tid - 400);
    const int  rb = (tid < 400) ? 0 : 1;
    const float wi_r = W_ih[rr];
    const float bi_r = b_ih[rr] + b_hh[rr];
    const bool  is_g = (rr >= 200) && (rr < 300);
    const float gm   = is_g ? 2.f : 1.f;       // tanh(u) = 2*sigm(2u)-1
    const float gb   = is_g ? -1.f : 0.f;

    // ---- B role: tid<200. u = unit, ub = batch. c-state in register.
    const int u  = (tid < 200) ? (tid % 100) : 0;
    const int ub = (tid < 200) ? (tid / 100) : 0;
    float cst = 0.f;

    // ---- C role: wave 13 = batch0, wave 14 = batch1 (out projection).
    const float wo0 = W_out[lane];                             // lane<64<100
    const float wo1 = (lane < HID - 64) ? W_out[64 + lane] : 0.f;
    const float bo  = b_out[0];

    if (tid < 128) { h0_s[tid] = 0.f; h1_s[tid] = 0.f; }
    __syncthreads();

    #pragma unroll 1
    for (int t = 0; t < TLEN; ++t) {
        // ---- Phase A: K-blocked dot partials, both batches.
        if (isA) {
            const float* h0p = h0_s + kb;
            const float* h1p = h1_s + kb;
            float s00 = 0.f, s01 = 0.f, s10 = 0.f, s11 = 0.f;
            float s20 = 0.f, s21 = 0.f, s30 = 0.f, s31 = 0.f;
            #pragma unroll
            for (int j = 0; j < 10; ++j) {
                float ha = h0p[j];             // 10 distinct addrs/wave: free
                float hb = h1p[j];
                s00 = fmaf(ha, w[0][j], s00);
                s01 = fmaf(hb, w[0][j], s01);
                s10 = fmaf(ha, w[1][j], s10);
                s11 = fmaf(hb, w[1][j], s11);
                s20 = fmaf(ha, w[2][j], s20);
                s21 = fmaf(hb, w[2][j], s21);
                s30 = fmaf(ha, w[3][j], s30);
                s31 = fmaf(hb, w[3][j], s31);
                if ((j & 3) == 3) __builtin_amdgcn_sched_barrier(0);
            }
            // partials: part_s[b][row][c], row stride 11 (<=2-way banks)
            const int pb = 44 * g + c;         // (4g)*11 + c
            part_s[pb]           = s00;
            part_s[pb + 11]      = s10;
            part_s[pb + 22]      = s20;
            part_s[pb + 33]      = s30;
            part_s[4400 + pb]      = s01;
            part_s[4400 + pb + 11] = s11;
            part_s[4400 + pb + 22] = s21;
            part_s[4400 + pb + 33] = s31;
        }
        __syncthreads();

        // ---- Phase R: reduce 10 partials + x-proj + activation (800 thr).
        if (tid < 800) {
            const float* pp = part_s + rb * 4400 + rr * PSTR;
            float s = ((pp[0] + pp[1]) + (pp[2] + pp[3]))
                    + ((pp[4] + pp[5]) + (pp[6] + pp[7]))
                    + (pp[8] + pp[9]);
            const float x = rb ? in1_s[t] : in0_s[t];
            float uu = fmaf(x, wi_r, bi_r) + s;
            float v  = __builtin_amdgcn_rcpf(1.f + __expf(-gm * uu));
            g_s[rb * NROW + rr] = fmaf(gm, v, gb);
        } else if (wave == 13 || wave == 14) {
            // ---- Phase C (lagged): out[b, t-1] from h(t-1), still stable.
            if (t > 0) {
                const float* hs = (wave == 13) ? h0_s : h1_s;
                float p = fmaf(hs[64 + lane], wo1, hs[lane] * wo0);
                #pragma unroll
                for (int off = 32; off > 0; off >>= 1)
                    p += __shfl_down(p, off);
                if (lane == 0)
                    out[(b0 + (wave - 13)) * TLEN + (t - 1)] = p + bo;
            }
        }
        __syncthreads();

        // ---- Phase B: cell update (200 threads).
        if (tid < 200) {
            const float* gs = g_s + ub * NROW;
            float ig = gs[u];
            float fg = gs[100 + u];
            float gg = gs[200 + u];
            float og = gs[300 + u];
            cst = fmaf(fg, cst, ig * gg);
            float th = 1.f - 2.f * __builtin_amdgcn_rcpf(__expf(2.f * cst) + 1.f);
            (ub ? h1_s : h0_s)[u] = og * th;
        }
        __syncthreads();
    }

    // Final output column t = TLEN-1 (h(T-1) is stable after last barrier).
    if (wave == 13 || wave == 14) {
        const float* hs = (wave == 13) ? h0_s : h1_s;
        float p = fmaf(hs[64 + lane], wo1, hs[lane] * wo0);
        #pragma unroll
        for (int off = 32; off > 0; off >>= 1)
            p += __shfl_down(p, off);
        if (lane == 0)
            out[(b0 + (wave - 13)) * TLEN + (TLEN - 1)] = p + bo;
    }
}

extern "C" void kernel_launch(void* const* d_in, const int* in_sizes, int n_in,
                              void* d_out, int out_size, void* d_ws, size_t ws_size,
                              hipStream_t stream) {
    const float* input = (const float*)d_in[0];
    const float* W_ih  = (const float*)d_in[1];
    const float* W_hh  = (const float*)d_in[2];
    const float* b_ih  = (const float*)d_in[3];
    const float* b_hh  = (const float*)d_in[4];
    const float* W_out = (const float*)d_in[5];
    const float* b_out = (const float*)d_in[6];
    float* out = (float*)d_out;

    const int B = in_sizes[0] / TLEN;  // 512
    lstm_kblock<<<B / 2, BLOCK, 0, stream>>>(input, W_ih, W_hh, b_ih, b_hh,
                                             W_out, b_out, out);
}

// Round 6
// 1165.899 us; speedup vs baseline: 1.5780x; 1.1014x over previous
//
#include <hip/hip_runtime.h>

// LSTM, B=512 x T=1024, H=100, input_size=1.
// R10: R4/R6/R9 (420 vs 600 LDS-ops, 1.5M vs 66M conflicts, VALUBusy 57-67%)
// all land at 1250-1285 us -> not LDS-throughput, not conflict, not VALU
// bound. The invariant: ONE block per CU + 2-3 barriers/step + LDS round
// trips => ~1500 cyc/step of un-hideable stall (no co-resident work).
// Fix: 2 blocks/CU (512 blocks x 1024 thr, 1 batch each). Requires <=64
// VGPR (8 waves/SIMD):
//   - A role: R=2 rows, K=20 (5 chunks): 40 weight regs + 4 acc, h read as
//     5 broadcast ds_read_b128 with sched_barrier caps (<=2 in flight).
//     jobs = 200 pairs x 5 chunks = 1000 threads.
//   - per-step constants (W_ih, b, W_out, b_out) live in LDS, not regs:
//     RB threads persist only c (1 reg).
//   - partials: float2 [5][201] (b64 write, row-adjacent pair).
// Phases: A -> barrier -> { RB (tid<100: reduce 20 partials + gates + cell,
// writes h and hw = h*W_out into parity-buffered stash) || C (wave 2:
// reduce hw of step t-1, store out) } -> barrier. 2 barriers/step.
// Stalls of one block overlap compute of the other.

#define HID   100
#define TLEN  1024
#define BLOCK 1024
#define NROW  400
#define PCH   402            // partial row stride in floats (= 201 float2)

__global__ __launch_bounds__(BLOCK, 8)
void lstm_2cu(
    const float* __restrict__ input,   // [B, T]
    const float* __restrict__ W_ih,    // [4H]
    const float* __restrict__ W_hh,    // [4H, H]
    const float* __restrict__ b_ih,    // [4H]
    const float* __restrict__ b_hh,    // [4H]
    const float* __restrict__ W_out,   // [H]
    const float* __restrict__ b_out,   // [1]
    float* __restrict__ out)           // [B, T]
{
    const int b    = blockIdx.x;
    const int tid  = threadIdx.x;
    const int wave = tid >> 6;

    __shared__ float4 h4_s[32];            // h: 128 floats (0..99 used)
    __shared__ float2 part2_s[5 * 201];    // partials, 8-byte aligned
    __shared__ float  hw_s[2 * 128];       // parity-buffered h*W_out
    __shared__ float  in_s[TLEN];
    __shared__ float  wib_s[NROW];         // W_ih
    __shared__ float  bib_s[NROW];         // b_ih + b_hh
    __shared__ float  wo_s[128];           // W_out (100 used)
    __shared__ float  bo_s;

    float*       h_s    = (float*)h4_s;
    const float* part_s = (const float*)part2_s;

    // One-time staging (coalesced / tiny).
    for (int i = tid; i < TLEN; i += BLOCK) in_s[i] = input[b * TLEN + i];
    if (tid < NROW) { wib_s[tid] = W_ih[tid]; bib_s[tid] = b_ih[tid] + b_hh[tid]; }
    if (tid >= 512 && tid < 512 + HID) wo_s[tid - 512] = W_out[tid - 512];
    if (tid == BLOCK - 1) bo_s = b_out[0];
    if (tid < 128) h_s[tid] = 0.f;

    // ---- A role: tid<1000. pair p = tid%200 (rows 2p,2p+1), chunk = tid/200
    // (k in [20c, 20c+20)). 40 weight VGPRs, plain loads (no asm pin).
    const bool isA = (tid < 1000);
    const int  p   = isA ? (tid % 200) : 0;
    const int  ch  = isA ? (tid / 200) : 0;
    float w0[20], w1[20];
    {
        const float* wr = W_hh + (2 * p) * HID + 20 * ch;
        #pragma unroll
        for (int j = 0; j < 20; ++j) { w0[j] = wr[j]; w1[j] = wr[HID + j]; }
    }

    float c = 0.f;                         // cell state (tid<100 only)
    __syncthreads();

    #pragma unroll 1
    for (int t = 0; t < TLEN; ++t) {
        // ---- Phase A: 2-row x 20-k dot partials (broadcast b128 h reads).
        if (isA) {
            const float4* hp = (const float4*)h4_s + 5 * ch;
            float a0 = 0.f, a1 = 0.f, d0 = 0.f, d1 = 0.f;
            #pragma unroll
            for (int jj = 0; jj < 5; ++jj) {
                float4 hv = hp[jj];        // one addr per ~wave: broadcast
                a0 = fmaf(hv.x, w0[4*jj+0], a0);
                a1 = fmaf(hv.y, w0[4*jj+1], a1);
                d0 = fmaf(hv.x, w1[4*jj+0], d0);
                d1 = fmaf(hv.y, w1[4*jj+1], d1);
                a0 = fmaf(hv.z, w0[4*jj+2], a0);
                a1 = fmaf(hv.w, w0[4*jj+3], a1);
                d0 = fmaf(hv.z, w1[4*jj+2], d0);
                d1 = fmaf(hv.w, w1[4*jj+3], d1);
                // cap in-flight h reads so peak regs stay < 64
                if (jj == 1 || jj == 3) __builtin_amdgcn_sched_barrier(0);
            }
            float2 pr; pr.x = a0 + a1; pr.y = d0 + d1;
            part2_s[ch * 201 + p] = pr;    // rows 2p,2p+1 of chunk ch
        }
        __syncthreads();

        // ---- Phase RB: reduce 5 chunks x 4 gates + cell update (100 thr).
        if (tid < HID) {
            const float* pp = part_s + tid;
            float s0 = ((pp[0]     + pp[PCH])       + (pp[2*PCH]     + pp[3*PCH]))     + pp[4*PCH];
            const float* q1 = pp + 100;
            float s1 = ((q1[0]     + q1[PCH])       + (q1[2*PCH]     + q1[3*PCH]))     + q1[4*PCH];
            const float* q2 = pp + 200;
            float s2 = ((q2[0]     + q2[PCH])       + (q2[2*PCH]     + q2[3*PCH]))     + q2[4*PCH];
            const float* q3 = pp + 300;
            float s3 = ((q3[0]     + q3[PCH])       + (q3[2*PCH]     + q3[3*PCH]))     + q3[4*PCH];
            const float x = in_s[t];
            float ig = fmaf(x, wib_s[tid],       bib_s[tid])       + s0;
            float fg = fmaf(x, wib_s[100 + tid], bib_s[100 + tid]) + s1;
            float gg = fmaf(x, wib_s[200 + tid], bib_s[200 + tid]) + s2;
            float og = fmaf(x, wib_s[300 + tid], bib_s[300 + tid]) + s3;
            float is = __builtin_amdgcn_rcpf(1.f + __expf(-ig));
            float fs = __builtin_amdgcn_rcpf(1.f + __expf(-fg));
            float os = __builtin_amdgcn_rcpf(1.f + __expf(-og));
            float gt = 1.f - 2.f * __builtin_amdgcn_rcpf(__expf(2.f * gg) + 1.f);
            c = fmaf(fs, c, is * gt);
            float th = 1.f - 2.f * __builtin_amdgcn_rcpf(__expf(2.f * c) + 1.f);
            float hn = os * th;
            h_s[tid] = hn;
            hw_s[(t & 1) * 128 + tid] = hn * wo_s[tid];   // stash h*W_out
        } else if (wave == 2) {
            // ---- Phase C (lagged 1 step): out[b,t-1] = sum(hw(t-1)) + bo.
            // Reads parity (t-1)&1 while RB writes (t&1): disjoint.
            if (t > 0) {
                const float* hw = hw_s + ((t - 1) & 1) * 128;
                const int l = tid - 128;
                float v = hw[l] + ((l < HID - 64) ? hw[64 + l] : 0.f);
                #pragma unroll
                for (int off = 32; off > 0; off >>= 1)
                    v += __shfl_down(v, off);
                if (l == 0) out[b * TLEN + (t - 1)] = v + bo_s;
            }
        }
        __syncthreads();
    }

    // Final column t = TLEN-1 (hw parity (TLEN-1)&1, stable after last barrier)
    if (wave == 2) {
        const float* hw = hw_s + ((TLEN - 1) & 1) * 128;
        const int l = tid - 128;
        float v = hw[l] + ((l < HID - 64) ? hw[64 + l] : 0.f);
        #pragma unroll
        for (int off = 32; off > 0; off >>= 1)
            v += __shfl_down(v, off);
        if (l == 0) out[b * TLEN + (TLEN - 1)] = v + bo_s;
    }
}

extern "C" void kernel_launch(void* const* d_in, const int* in_sizes, int n_in,
                              void* d_out, int out_size, void* d_ws, size_t ws_size,
                              hipStream_t stream) {
    const float* input = (const float*)d_in[0];
    const float* W_ih  = (const float*)d_in[1];
    const float* W_hh  = (const float*)d_in[2];
    const float* b_ih  = (const float*)d_in[3];
    const float* b_hh  = (const float*)d_in[4];
    const float* W_out = (const float*)d_in[5];
    const float* b_out = (const float*)d_in[6];
    float* out = (float*)d_out;

    const int B = in_sizes[0] / TLEN;  // 512
    lstm_2cu<<<B, BLOCK, 0, stream>>>(input, W_ih, W_hh, b_ih, b_hh,
                                      W_out, b_out, out);
}

// Round 7
// 1037.936 us; speedup vs baseline: 1.7726x; 1.1233x over previous
//
#include <hip/hip_runtime.h>

// LSTM, B=512 x T=1024, H=100, input_size=1.
// R11: R4 vs R10 normalize to an IDENTICAL 1450 cyc per batch-step despite
// 2x occupancy difference -> throughput-bound on VALU ISSUE (VALUBusy 46% x
// 2912 = 1340 cyc of issue per step, matching instr count), not latency,
// not LDS, not weight reloads (VGPR=32 + no FETCH growth => weights are
// resident as hidden AGPRs in the unified file).
// Attack instruction count, two ways:
//  1) v_pk_fma_f32 (VOP3P packed fp32, 2 MACs/instr): 625 -> 312 wave-instr
//     of FMA per batch-step.
//  2) BLOCK=512 (2 blocks/CU, 4 waves/SIMD -> 128-reg budget): A-role =
//     500 thr x (R=4 rows, K=20): 80 weight floats as 40 v2f; per-thread
//     overhead (5 b128 h-reads, 1 b128 partial write, addresses) now
//     amortizes over 80 MACs -> misc instr count halves vs R10.
// Phases: A (500 thr) -> barrier -> { RB (100 thr: 20 partial reads +
// gates + cell + h/hw write) || C (wave 2: lagged out-projection from
// parity hw stash) } -> barrier. Per-step constants in LDS.

#define HID   100
#define TLEN  1024
#define BLOCK 512

typedef float v2f __attribute__((ext_vector_type(2)));
typedef float v4f __attribute__((ext_vector_type(4)));

// D = S0*S1 + D, two f32 lanes per instruction (CDNA packed fp32).
#define PKFMA(A, B, C) asm("v_pk_fma_f32 %0, %1, %2, %0" : "+v"(A) : "v"(B), "v"(C))

__global__ __launch_bounds__(BLOCK, 4)
void lstm_pk(
    const float* __restrict__ input,   // [B, T]
    const float* __restrict__ W_ih,    // [4H]
    const float* __restrict__ W_hh,    // [4H, H]
    const float* __restrict__ b_ih,    // [4H]
    const float* __restrict__ b_hh,    // [4H]
    const float* __restrict__ W_out,   // [H]
    const float* __restrict__ b_out,   // [1]
    float* __restrict__ out)           // [B, T]
{
    const int b    = blockIdx.x;
    const int tid  = threadIdx.x;
    const int lane = tid & 63;
    const int wave = tid >> 6;

    __shared__ v4f   h4_s[32];          // h: 128 floats (0..99 used, pad 0)
    __shared__ v4f   part4_s[505];      // partials: [5 chunks][404 floats]
    __shared__ float hw_s[2 * 128];     // parity-buffered h*W_out
    __shared__ float in_s[TLEN];
    __shared__ float wib_s[4 * HID];    // W_ih
    __shared__ float bib_s[4 * HID];    // b_ih + b_hh
    __shared__ float wo_s[128];         // W_out (100 used)
    __shared__ float bo_s;

    float* h_s = (float*)h4_s;

    // One-time staging.
    for (int i = tid; i < TLEN; i += BLOCK) in_s[i] = input[b * TLEN + i];
    if (tid < 4 * HID) { wib_s[tid] = W_ih[tid]; bib_s[tid] = b_ih[tid] + b_hh[tid]; }
    if (tid < 128) { h_s[tid] = 0.f; wo_s[tid] = (tid < HID) ? W_out[tid] : 0.f; }
    if (tid == 0) bo_s = b_out[0];

    // ---- A role: tid<500. g = tid%100 (rows 4g..4g+3), ch = tid/100
    // (k in [20ch, 20ch+20)). Weights: 4 rows x 10 v2f = 80 VGPRs.
    const bool isA = (tid < 500);
    const int  g   = isA ? (tid % 100) : 0;
    const int  ch  = isA ? (tid / 100) : 0;
    v2f w2[4][10];
    #pragma unroll
    for (int r = 0; r < 4; ++r) {
        const v2f* wr = (const v2f*)(W_hh + (4 * g + r) * HID + 20 * ch);
        #pragma unroll
        for (int j = 0; j < 10; ++j) {
            v2f v = wr[j];
            asm volatile("" : "+v"(v));   // pin: block remat of the load
            w2[r][j] = v;
        }
    }

    float c = 0.f;                        // cell state (tid<100 only)
    __syncthreads();

    #pragma unroll 1
    for (int t = 0; t < TLEN; ++t) {
        // ---- Phase A: 4-row x 20-k packed dot partials.
        {
            const v4f* hp = (const v4f*)h4_s + 5 * ch;
            v2f a0 = {0.f, 0.f}, a1 = {0.f, 0.f};
            v2f a2 = {0.f, 0.f}, a3 = {0.f, 0.f};
            #pragma unroll
            for (int jj = 0; jj < 5; ++jj) {
                v4f hv = hp[jj];           // <=2 distinct addrs/wave: bcast
                v2f hlo = __builtin_shufflevector(hv, hv, 0, 1);
                v2f hhi = __builtin_shufflevector(hv, hv, 2, 3);
                PKFMA(a0, hlo, w2[0][2 * jj]); PKFMA(a0, hhi, w2[0][2 * jj + 1]);
                PKFMA(a1, hlo, w2[1][2 * jj]); PKFMA(a1, hhi, w2[1][2 * jj + 1]);
                PKFMA(a2, hlo, w2[2][2 * jj]); PKFMA(a2, hhi, w2[2][2 * jj + 1]);
                PKFMA(a3, hlo, w2[3][2 * jj]); PKFMA(a3, hhi, w2[3][2 * jj + 1]);
            }
            if (isA) {
                v4f pr;
                pr.x = a0.x + a0.y; pr.y = a1.x + a1.y;
                pr.z = a2.x + a2.y; pr.w = a3.x + a3.y;
                part4_s[101 * ch + g] = pr;   // rows 4g..4g+3 of chunk ch
            }
        }
        __syncthreads();

        // ---- Phase RB: reduce 5 chunks x 4 gates + cell update (100 thr).
        if (tid < HID) {
            const float* ps = (const float*)part4_s;
            float s0 = 0.f, s1 = 0.f, s2 = 0.f, s3 = 0.f;
            #pragma unroll
            for (int cc = 0; cc < 5; ++cc) {
                const float* pp = ps + 404 * cc + tid;   // row = gate*100+tid
                s0 += pp[0];
                s1 += pp[100];
                s2 += pp[200];
                s3 += pp[300];
            }
            const float x = in_s[t];
            float ig = fmaf(x, wib_s[tid],           bib_s[tid])           + s0;
            float fg = fmaf(x, wib_s[HID + tid],     bib_s[HID + tid])     + s1;
            float gg = fmaf(x, wib_s[2 * HID + tid], bib_s[2 * HID + tid]) + s2;
            float og = fmaf(x, wib_s[3 * HID + tid], bib_s[3 * HID + tid]) + s3;
            float is = __builtin_amdgcn_rcpf(1.f + __expf(-ig));
            float fs = __builtin_amdgcn_rcpf(1.f + __expf(-fg));
            float os = __builtin_amdgcn_rcpf(1.f + __expf(-og));
            float gt = 1.f - 2.f * __builtin_amdgcn_rcpf(__expf(2.f * gg) + 1.f);
            c = fmaf(fs, c, is * gt);
            float th = 1.f - 2.f * __builtin_amdgcn_rcpf(__expf(2.f * c) + 1.f);
            float hn = os * th;
            h_s[tid] = hn;
            hw_s[(t & 1) * 128 + tid] = hn * wo_s[tid];  // stash h*W_out
        } else if (wave == 2) {
            // ---- Phase C (lagged 1 step): out[b,t-1] = sum(hw(t-1)) + bo.
            if (t > 0) {
                const float* hw = hw_s + ((t - 1) & 1) * 128;
                float v = hw[lane] + ((lane < HID - 64) ? hw[64 + lane] : 0.f);
                #pragma unroll
                for (int off = 32; off > 0; off >>= 1)
                    v += __shfl_down(v, off);
                if (lane == 0) out[b * TLEN + (t - 1)] = v + bo_s;
            }
        }
        __syncthreads();
    }

    // Final column t = TLEN-1.
    if (wave == 2) {
        const float* hw = hw_s + ((TLEN - 1) & 1) * 128;
        float v = hw[lane] + ((lane < HID - 64) ? hw[64 + lane] : 0.f);
        #pragma unroll
        for (int off = 32; off > 0; off >>= 1)
            v += __shfl_down(v, off);
        if (lane == 0) out[b * TLEN + (TLEN - 1)] = v + bo_s;
    }
}

extern "C" void kernel_launch(void* const* d_in, const int* in_sizes, int n_in,
                              void* d_out, int out_size, void* d_ws, size_t ws_size,
                              hipStream_t stream) {
    const float* input = (const float*)d_in[0];
    const float* W_ih  = (const float*)d_in[1];
    const float* W_hh  = (const float*)d_in[2];
    const float* b_ih  = (const float*)d_in[3];
    const float* b_hh  = (const float*)d_in[4];
    const float* W_out = (const float*)d_in[5];
    const float* b_out = (const float*)d_in[6];
    float* out = (float*)d_out;

    const int B = in_sizes[0] / TLEN;  // 512
    lstm_pk<<<B, BLOCK, 0, stream>>>(input, W_ih, W_hh, b_ih, b_hh,
                                     W_out, b_out, out);
}